// Round 7
// baseline (376.045 us; speedup 1.0000x reference)
//
#include <hip/hip_runtime.h>
#include <stdint.h>

typedef __attribute__((ext_vector_type(8))) short short8;
typedef __attribute__((ext_vector_type(4))) float f32x4;
typedef __attribute__((ext_vector_type(16))) float f32x16;
typedef __attribute__((ext_vector_type(4))) unsigned short u16x4;

typedef unsigned short u16;

constexpr int S_LEN = 2048;
constexpr int DH    = 128;

__device__ __forceinline__ u16 f2bf(float f) {
    union { float f; unsigned u; } v; v.f = f;
    unsigned r = v.u + 0x7FFFu + ((v.u >> 16) & 1u);
    return (u16)(r >> 16);
}
__device__ __forceinline__ unsigned cvt_pk_bf16(float lo, float hi) {
    unsigned r;
    asm("v_cvt_pk_bf16_f32 %0, %1, %2" : "=v"(r) : "v"(lo), "v"(hi));
    return r;
}
__device__ __forceinline__ void gl_lds16(const void* g, void* l) {
    __builtin_amdgcn_global_load_lds((const __attribute__((address_space(1))) void*)g,
                                     (__attribute__((address_space(3))) void*)l,
                                     16, 0, 0);
}

// ---------- fp32 -> bf16 bulk convert ----------
__global__ __launch_bounds__(256) void convx(const float* __restrict__ src,
                                             u16* __restrict__ dst) {
    size_t i = ((size_t)blockIdx.x * 256 + threadIdx.x) * 8;
    f32x4 a = *(const f32x4*)(src + i);
    f32x4 b = *(const f32x4*)(src + i + 4);
    short8 r;
    r[0] = (short)f2bf(a[0]); r[1] = (short)f2bf(a[1]);
    r[2] = (short)f2bf(a[2]); r[3] = (short)f2bf(a[3]);
    r[4] = (short)f2bf(b[0]); r[5] = (short)f2bf(b[1]);
    r[6] = (short)f2bf(b[2]); r[7] = (short)f2bf(b[3]);
    *(short8*)(dst + i) = r;
}

// ---------- fused transpose-convert for Wqkv AND Wproj (one dispatch) -------
// 64x64 tile, 256 threads, float4 loads, u16x4 stores through padded LDS.
// bx < 96 -> Wqkv (cols 6144); bx >= 96 -> Wproj (cols 2048). rows = 2048.
__global__ __launch_bounds__(256) void convT2(const float* __restrict__ s1,
                                              u16* __restrict__ d1,
                                              const float* __restrict__ s2,
                                              u16* __restrict__ d2) {
    __shared__ u16 t[64][65];
    const int bx = blockIdx.x;
    const bool first = bx < 96;
    const float* src = first ? s1 : s2;
    u16* dst = first ? d1 : d2;
    const int cols = first ? 6144 : 2048;
    const int c0 = (first ? bx : bx - 96) * 64;
    const int r0 = blockIdx.y * 64;
    const int rows = 2048;
    const int tid = threadIdx.x;
    const int colq = (tid & 15) * 4;
    const int rw   = tid >> 4;
#pragma unroll
    for (int p = 0; p < 4; ++p) {
        int row = p * 16 + rw;
        f32x4 v = *(const f32x4*)(src + (size_t)(r0 + row) * cols + c0 + colq);
        t[colq + 0][row] = f2bf(v[0]);
        t[colq + 1][row] = f2bf(v[1]);
        t[colq + 2][row] = f2bf(v[2]);
        t[colq + 3][row] = f2bf(v[3]);
    }
    __syncthreads();
    const int rowq = (tid & 15) * 4;
    const int cw   = tid >> 4;
#pragma unroll
    for (int p = 0; p < 4; ++p) {
        int col = p * 16 + cw;
        u16x4 o;
        o[0] = t[col][rowq + 0]; o[1] = t[col][rowq + 1];
        o[2] = t[col][rowq + 2]; o[3] = t[col][rowq + 3];
        *(u16x4*)(dst + (size_t)(c0 + col) * rows + r0 + rowq) = o;
    }
}

// ================= QKV GEMM: 128x256 tile, BK=64, 8-wave, counted-vmcnt =====
// (round-3/5 verified: ~111us, MfmaUtil ~39%, 0 bank conflicts)
__global__ __launch_bounds__(512, 2) void gemm_qkv(
        const u16* __restrict__ A, const u16* __restrict__ BT,
        u16* __restrict__ Qo, u16* __restrict__ Ko, u16* __restrict__ VTo) {
    __shared__ __align__(16) u16 lA[2][128 * 64];   // 16KB x2
    __shared__ __align__(16) u16 lB[2][256 * 64];   // 32KB x2
    const int tid = threadIdx.x;
    const int lane = tid & 63, wave = tid >> 6;
    const int quad = lane >> 4, l16 = lane & 15;
    const int wr = wave >> 2, wc = wave & 3;
    const int m0 = blockIdx.y * 128, n0 = blockIdx.x * 256;
    const int sw = l16 & 7;                 // read-side swizzle key (== row&7)
    const int c4 = tid & 7;                 // stage chunk index
    f32x4 acc[4][4] = {};

    auto stageA = [&](int t1, int nb) {     // 128x64 tile, 2 loads/thread
#pragma unroll
        for (int j = 0; j < 2; ++j) {
            int idx = j * 512 + tid;
            int row = idx >> 3;
            gl_lds16(A + (size_t)(m0 + row) * 2048 + t1 * 64 + ((c4 ^ (row & 7)) * 8),
                     &lA[nb][row * 64 + c4 * 8]);
        }
    };
    auto stageB = [&](int h, int t1, int nb) {  // 128 rows (bit5==h), 2 loads
#pragma unroll
        for (int j = 0; j < 2; ++j) {
            int rih = (j * 512 + tid) >> 3;
            int row = (rih & 31) + h * 32 + (rih >> 5) * 64;
            gl_lds16(BT + (size_t)(n0 + row) * 2048 + t1 * 64 + ((c4 ^ (row & 7)) * 8),
                     &lB[nb][row * 64 + c4 * 8]);
        }
    };

    // prologue: tile 0 -> queue [A0:2, B0h0:2, B0h1:2]
    stageA(0, 0); stageB(0, 0, 0); stageB(1, 0, 0);

    constexpr int NT = 32;
    for (int t = 0; t < NT; ++t) {
        const int buf = t & 1, nb = buf ^ 1;
        const bool pf = (t + 1 < NT);
        // ---- W0: A(t), B-h0(t) landed everywhere ----
        asm volatile("s_waitcnt vmcnt(2)\n\ts_barrier" ::: "memory");
        // ---- R0: all A frags + B half0 frags ----
        short8 af[4][2], bf0[2][2];
        const int abase = (wr * 64 + l16) * 64;
        const int bbase = (wc * 64 + l16) * 64;
#pragma unroll
        for (int m = 0; m < 4; ++m)
#pragma unroll
            for (int ks = 0; ks < 2; ++ks)
                af[m][ks] = *(const short8*)&lA[buf][abase + m * 1024 + (((ks * 4 + quad) ^ sw)) * 8];
#pragma unroll
        for (int n = 0; n < 2; ++n)
#pragma unroll
            for (int ks = 0; ks < 2; ++ks)
                bf0[n][ks] = *(const short8*)&lB[buf][bbase + n * 1024 + (((ks * 4 + quad) ^ sw)) * 8];
        // ---- G0: stage A(t+1), B0(t+1) ----
        if (pf) { stageA(t + 1, nb); stageB(0, t + 1, nb); }
        // ---- M0: 16 MFMA (n-half 0) ----
        __builtin_amdgcn_s_setprio(1);
#pragma unroll
        for (int m = 0; m < 4; ++m)
#pragma unroll
            for (int n = 0; n < 2; ++n)
#pragma unroll
                for (int ks = 0; ks < 2; ++ks)
                    acc[m][n] = __builtin_amdgcn_mfma_f32_16x16x32_bf16(
                        af[m][ks], bf0[n][ks], acc[m][n], 0, 0, 0);
        __builtin_amdgcn_s_setprio(0);
        // ---- W1: B-h1(t) landed everywhere (keep t+1's 4 in flight) ----
        if (pf) asm volatile("s_waitcnt vmcnt(4)\n\ts_barrier" ::: "memory");
        else    asm volatile("s_waitcnt vmcnt(0)\n\ts_barrier" ::: "memory");
        // ---- R1: B half1 frags ----
        short8 bf1[2][2];
#pragma unroll
        for (int n = 0; n < 2; ++n)
#pragma unroll
            for (int ks = 0; ks < 2; ++ks)
                bf1[n][ks] = *(const short8*)&lB[buf][bbase + 2048 + n * 1024 + (((ks * 4 + quad) ^ sw)) * 8];
        // ---- G1: stage B1(t+1) ----
        if (pf) stageB(1, t + 1, nb);
        // ---- M1: 16 MFMA (n-half 1) ----
        __builtin_amdgcn_s_setprio(1);
#pragma unroll
        for (int m = 0; m < 4; ++m)
#pragma unroll
            for (int n = 0; n < 2; ++n)
#pragma unroll
                for (int ks = 0; ks < 2; ++ks)
                    acc[m][n + 2] = __builtin_amdgcn_mfma_f32_16x16x32_bf16(
                        af[m][ks], bf1[n][ks], acc[m][n + 2], 0, 0, 0);
        __builtin_amdgcn_s_setprio(0);
    }

    // ---- epilogue: split to Q / K / VT ----
#pragma unroll
    for (int m = 0; m < 4; ++m) {
        int r0r = m0 + wr * 64 + m * 16 + quad * 4;
        int b = r0r >> 11, s0 = r0r & 2047;
#pragma unroll
        for (int n = 0; n < 4; ++n) {
            int cc = n0 + wc * 64 + n * 16 + l16;
            int which = cc >> 11, hd = (cc >> 7) & 15, dh = cc & 127;
            if (which < 2) {
                u16* dst = which == 0 ? Qo : Ko;
#pragma unroll
                for (int rg = 0; rg < 4; ++rg)
                    dst[(size_t)((b * 16 + hd) * 2048 + s0 + rg) * 128 + dh] = f2bf(acc[m][n][rg]);
            } else {
                u16x4 v;
#pragma unroll
                for (int rg = 0; rg < 4; ++rg) v[rg] = f2bf(acc[m][n][rg]);
                *(u16x4*)&VTo[((size_t)(b * 16 + hd) * 128 + dh) * 2048 + s0] = v;
            }
        }
    }
}

// ================= flash attention (32x32 swapped-QK, counted-vmcnt) ========
// grid (16,32): bx = qb DIRECTLY, by = head. EQUAL-LENGTH CO-RESIDENCY: the
// two blocks sharing a CU (ids paired consecutively or at stride 256 under
// any regular dispatch map) now have the SAME (or +-1) iteration count, so
// the CU keeps 2 waves/SIMD for the WHOLE kernel. The old LPT pairing put a
// 32-iter block with a 2-iter block: the light one died early and the heavy
// one ran at 1 wave/SIMD (zero latency hiding) for ~94% of its life --
// makespan ~31 t_solo vs ~19 t_solo here.
// Counted-vmcnt staging (round 6): 4 loads stay in flight across every
// barrier; K-latency hides under softmax, V-latency under QK^T.
__global__ __launch_bounds__(256, 2) void attn_kern(
        u16* __restrict__ QOp, const u16* __restrict__ Kp,
        const u16* __restrict__ VTp) {
    __shared__ __align__(16) u16 lK[2][64 * 128];   // 16KB x2
    __shared__ __align__(16) u16 lV[2][128 * 64];   // 16KB x2
    const int tid = threadIdx.x, lane = tid & 63, wave = tid >> 6;
    const int ql = lane & 31, hi = lane >> 5;
    const int qb = blockIdx.x;                 // equal-length pairing
    const int bh = blockIdx.y;
    const int qbase = qb * 128 + wave * 32;
    const int qmax = qbase + 31;
    const int nkt = 2 * qb + 2;
    u16* Qh = QOp + (size_t)bh * S_LEN * DH;
    const u16* Kh = Kp + (size_t)bh * S_LEN * DH;
    const u16* VTh = VTp + (size_t)bh * DH * S_LEN;

    // Q fragments (B-operand): lane holds q = qbase+ql, d = c*16 + hi*8 + j
    short8 qf[8];
#pragma unroll
    for (int c = 0; c < 8; ++c)
        qf[c] = *(const short8*)&Qh[(size_t)(qbase + ql) * 128 + c * 16 + hi * 8];

    f32x16 acc[4] = {};           // O: col d = dc*32+ql, rows q via reg index
    float mrun = -1e30f, lrun = 0.f;
    const float SC = 0.08838834764831845f * 1.44269504088896f; // scale*log2(e)

    auto stageK = [&](int kt, int b) {
        const u16* ks = Kh + (size_t)kt * 64 * 128;
#pragma unroll
        for (int p = 0; p < 4; ++p) {
            int slot = p * 256 + tid;
            int row = slot >> 4, c4 = slot & 15;
            gl_lds16(ks + row * 128 + ((c4 ^ (row & 15)) * 8), &lK[b][slot * 8]);
        }
    };
    auto stageV = [&](int kt, int b) {
        const u16* vs = VTh + kt * 64;
#pragma unroll
        for (int p = 0; p < 4; ++p) {
            int slot = p * 256 + tid;
            int row = slot >> 3, c4 = slot & 7;
            gl_lds16(vs + (size_t)row * 2048 + ((c4 ^ (row & 7)) * 8), &lV[b][slot * 8]);
        }
    };

    // prologue: K0 ready, V0:4 in flight
    stageK(0, 0);
    stageV(0, 0);
    asm volatile("s_waitcnt vmcnt(4)\n\ts_barrier" ::: "memory");

    for (int kt = 0; kt < nkt; ++kt) {
        const int buf = kt & 1;
        const bool more = kt + 1 < nkt;
        const bool compute = (kt * 64 <= qmax);   // wave-uniform causal skip
        float pv0[16], pv1[16];
        if (compute) {
            const bool part = (kt * 64 + 63 > qbase);
            // ---- QK^T swapped: D[k][q], two 32x32 tiles over KVBLK=64 ----
            f32x16 s0 = {}, s1 = {};
            __builtin_amdgcn_s_setprio(1);
#pragma unroll
            for (int c = 0; c < 8; ++c) {
                int sl = ((c * 2 + hi) ^ (ql & 15)) * 8;   // (32+ql)&15 == ql&15
                short8 k0 = *(const short8*)&lK[buf][ql * 128 + sl];
                short8 k1 = *(const short8*)&lK[buf][(32 + ql) * 128 + sl];
                s0 = __builtin_amdgcn_mfma_f32_32x32x16_bf16(k0, qf[c], s0, 0, 0, 0);
                s1 = __builtin_amdgcn_mfma_f32_32x32x16_bf16(k1, qf[c], s1, 0, 0, 0);
            }
            __builtin_amdgcn_s_setprio(0);
            // issue next K early: latency hides under softmax VALU below
            if (more) stageK(kt + 1, buf ^ 1);
            // ---- scale + (hoisted) causal mask + row max ----
            float pm = -1e30f;
            const int qg = qbase + ql;
            if (part) {
#pragma unroll
                for (int r = 0; r < 16; ++r) {
                    int krow = (r & 3) + 8 * (r >> 2) + 4 * hi;
                    float a = s0[r] * SC;
                    float b = s1[r] * SC;
                    if (kt * 64 + krow > qg)      a = -1e30f;
                    if (kt * 64 + 32 + krow > qg) b = -1e30f;
                    pv0[r] = a; pv1[r] = b;
                    pm = fmaxf(pm, fmaxf(a, b));
                }
            } else {
#pragma unroll
                for (int r = 0; r < 16; ++r) {
                    float a = s0[r] * SC;
                    float b = s1[r] * SC;
                    pv0[r] = a; pv1[r] = b;
                    pm = fmaxf(pm, fmaxf(a, b));
                }
            }
            pm = fmaxf(pm, __shfl_xor(pm, 32));
            // ---- defer-max rescale (rare) ----
            if (__any(pm - mrun > 8.f)) {
                float mn = fmaxf(mrun, pm);
                float al = exp2f(mrun - mn);
                mrun = mn;
                lrun *= al;
#pragma unroll
                for (int r = 0; r < 16; ++r) {
                    float ar = __shfl(al, (r & 3) + 8 * (r >> 2) + 4 * hi);
#pragma unroll
                    for (int dc = 0; dc < 4; ++dc)
                        acc[dc][r] *= ar;
                }
            }
            // ---- exp2 + row sum ----
            float rs = 0.f;
#pragma unroll
            for (int r = 0; r < 16; ++r) {
                pv0[r] = exp2f(pv0[r] - mrun);
                pv1[r] = exp2f(pv1[r] - mrun);
                rs += pv0[r] + pv1[r];
            }
            rs += __shfl_xor(rs, 32);
            lrun += rs;
        } else if (more) {
            stageK(kt + 1, buf ^ 1);
        }
        // ---- mid barrier: V(kt) landed everywhere; K(kt+1) stays in flight
        if (more) asm volatile("s_waitcnt vmcnt(4)\n\ts_barrier" ::: "memory");
        else      asm volatile("s_waitcnt vmcnt(0)\n\ts_barrier" ::: "memory");
        if (compute) {
            // ---- in-register P -> A-fragment repack (cvt_pk: 1 instr / pair)
            unsigned X0[8], X1[8];
#pragma unroll
            for (int i = 0; i < 8; ++i) {
                X0[i] = cvt_pk_bf16(pv0[2 * i], pv0[2 * i + 1]);
                X1[i] = cvt_pk_bf16(pv1[2 * i], pv1[2 * i + 1]);
            }
            short8 pa[4];
#pragma unroll
            for (int t = 0; t < 2; ++t)
#pragma unroll
                for (int h = 0; h < 2; ++h) {
                    unsigned x0 = t ? X1[4 * h + 0] : X0[4 * h + 0];
                    unsigned x1 = t ? X1[4 * h + 1] : X0[4 * h + 1];
                    unsigned x2 = t ? X1[4 * h + 2] : X0[4 * h + 2];
                    unsigned x3 = t ? X1[4 * h + 3] : X0[4 * h + 3];
                    unsigned sx0 = (unsigned)__shfl_xor((int)x0, 32);
                    unsigned sx1 = (unsigned)__shfl_xor((int)x1, 32);
                    unsigned sx2 = (unsigned)__shfl_xor((int)x2, 32);
                    unsigned sx3 = (unsigned)__shfl_xor((int)x3, 32);
                    union { unsigned u[4]; short8 s; } uf;
                    uf.u[0] = hi ? sx2 : x0;
                    uf.u[1] = hi ? sx3 : x1;
                    uf.u[2] = hi ? x2 : sx0;
                    uf.u[3] = hi ? x3 : sx1;
                    pa[t * 2 + h] = uf.s;
                }
            // ---- PV: O[q][d] += P[q][k] V[k][d] ----
            __builtin_amdgcn_s_setprio(1);
#pragma unroll
            for (int dc = 0; dc < 4; ++dc) {
                const int rv = dc * 32 + ql;
#pragma unroll
                for (int kc = 0; kc < 4; ++kc) {
                    short8 vf = *(const short8*)&lV[buf][rv * 64 + (((kc * 2 + hi) ^ (ql & 7)) * 8)];
                    acc[dc] = __builtin_amdgcn_mfma_f32_32x32x16_bf16(pa[kc], vf, acc[dc], 0, 0, 0);
                }
            }
            __builtin_amdgcn_s_setprio(0);
        }
        if (more) {
            stageV(kt + 1, buf ^ 1);
            // end barrier: K(kt+1) landed everywhere; V(kt+1) stays in flight
            asm volatile("s_waitcnt vmcnt(4)\n\ts_barrier" ::: "memory");
        }
    }

    // ---- epilogue: normalize by l (per-q, broadcast via shfl) and store ----
    float linv = 1.f / lrun;
#pragma unroll
    for (int r = 0; r < 16; ++r) {
        int qr = (r & 3) + 8 * (r >> 2) + 4 * hi;
        float lr = __shfl(linv, qr);
        int qq = qbase + qr;
#pragma unroll
        for (int dc = 0; dc < 4; ++dc)
            Qh[(size_t)qq * 128 + dc * 32 + ql] = f2bf(acc[dc][r] * lr);
    }
}

// ================= proj GEMM: 128x128 tile, 4-wave, 2 blocks/CU =============
// (round-5 state, kept)
__global__ __launch_bounds__(256, 2) void gemm_proj(
        const u16* __restrict__ QO, const u16* __restrict__ BT,
        const float* __restrict__ bias, float* __restrict__ out) {
    __shared__ __align__(16) u16 lA[2][128 * 64];   // 16KB x2
    __shared__ __align__(16) u16 lB[2][128 * 64];   // 16KB x2
    const int tid = threadIdx.x;
    const int lane = tid & 63, wave = tid >> 6;
    const int quad = lane >> 4, l16 = lane & 15;
    const int wm = wave >> 1, wn = wave & 1;
    const int bid = blockIdx.x;
    const int swz = (bid & 7) * 64 + (bid >> 3);     // XCD-chunked remap
    const int m0 = (swz >> 4) * 128, n0 = (swz & 15) * 128;
    const int sw = l16 & 7;
    const int c4 = tid & 7;
    f32x4 acc[4][4] = {};

    auto stageA = [&](int t1, int nb) {     // 128x64 from QO, 4 loads/thread
#pragma unroll
        for (int j = 0; j < 4; ++j) {
            int row = (j * 256 + tid) >> 3;
            int r = m0 + row;
            int b = r >> 11, s = r & 2047;
            int k = t1 * 64 + ((c4 ^ (row & 7)) * 8);
            int h = k >> 7, dh = k & 127;
            gl_lds16(QO + ((size_t)(b * 16 + h) * 2048 + s) * 128 + dh,
                     &lA[nb][row * 64 + c4 * 8]);
        }
    };
    auto stageB = [&](int h, int t1, int nb) {  // 64 rows (bit5==h), 2 loads
#pragma unroll
        for (int j = 0; j < 2; ++j) {
            int rih = (j * 256 + tid) >> 3;
            int row = (rih & 31) + h * 32 + (rih >> 5) * 64;
            gl_lds16(BT + (size_t)(n0 + row) * 2048 + t1 * 64 + ((c4 ^ (row & 7)) * 8),
                     &lB[nb][row * 64 + c4 * 8]);
        }
    };

    // prologue: FIFO [B0:2][A:4][B1:2]
    stageB(0, 0, 0);
    asm volatile("" ::: "memory");
    stageA(0, 0);
    asm volatile("" ::: "memory");
    stageB(1, 0, 0);

    constexpr int NT = 32;
    for (int t = 0; t < NT; ++t) {
        const int buf = t & 1, nb = buf ^ 1;
        const bool pf = (t + 1 < NT);
        // W0: B0(t)+A(t) landed (B1(t):2 stay in flight)
        asm volatile("s_waitcnt vmcnt(2)\n\ts_barrier" ::: "memory");
        short8 af[4][2], bf0[2][2];
        const int abase = (wm * 64 + l16) * 64;
        const int bbase = (wn * 64 + l16) * 64;
#pragma unroll
        for (int m = 0; m < 4; ++m)
#pragma unroll
            for (int ks = 0; ks < 2; ++ks)
                af[m][ks] = *(const short8*)&lA[buf][abase + m * 1024 + (((ks * 4 + quad) ^ sw)) * 8];
#pragma unroll
        for (int n = 0; n < 2; ++n)
#pragma unroll
            for (int ks = 0; ks < 2; ++ks)
                bf0[n][ks] = *(const short8*)&lB[buf][bbase + n * 1024 + (((ks * 4 + quad) ^ sw)) * 8];
        if (pf) {
            stageB(0, t + 1, nb);
            asm volatile("" ::: "memory");
            stageA(t + 1, nb);
        }
        __builtin_amdgcn_s_setprio(1);
#pragma unroll
        for (int m = 0; m < 4; ++m)
#pragma unroll
            for (int n = 0; n < 2; ++n)
#pragma unroll
                for (int ks = 0; ks < 2; ++ks)
                    acc[m][n] = __builtin_amdgcn_mfma_f32_16x16x32_bf16(
                        af[m][ks], bf0[n][ks], acc[m][n], 0, 0, 0);
        __builtin_amdgcn_s_setprio(0);
        // W1: B1(t) landed (t+1's B0:2 + A:4 = 6 stay in flight)
        if (pf) asm volatile("s_waitcnt vmcnt(6)\n\ts_barrier" ::: "memory");
        else    asm volatile("s_waitcnt vmcnt(0)\n\ts_barrier" ::: "memory");
        short8 bf1[2][2];
#pragma unroll
        for (int n = 0; n < 2; ++n)
#pragma unroll
            for (int ks = 0; ks < 2; ++ks)
                bf1[n][ks] = *(const short8*)&lB[buf][bbase + 2048 + n * 1024 + (((ks * 4 + quad) ^ sw)) * 8];
        if (pf) stageB(1, t + 1, nb);
        __builtin_amdgcn_s_setprio(1);
#pragma unroll
        for (int m = 0; m < 4; ++m)
#pragma unroll
            for (int n = 0; n < 2; ++n)
#pragma unroll
                for (int ks = 0; ks < 2; ++ks)
                    acc[m][n + 2] = __builtin_amdgcn_mfma_f32_16x16x32_bf16(
                        af[m][ks], bf1[n][ks], acc[m][n + 2], 0, 0, 0);
        __builtin_amdgcn_s_setprio(0);
    }

    // ---- epilogue: fp32 + bias ----
#pragma unroll
    for (int m = 0; m < 4; ++m) {
        int r0r = m0 + wm * 64 + m * 16 + quad * 4;
#pragma unroll
        for (int n = 0; n < 4; ++n) {
            int cc = n0 + wn * 64 + n * 16 + l16;
            float bv = bias[cc];
#pragma unroll
            for (int rg = 0; rg < 4; ++rg)
                out[(size_t)(r0r + rg) * 2048 + cc] = acc[m][n][rg] + bv;
        }
    }
}

extern "C" void kernel_launch(void* const* d_in, const int* in_sizes, int n_in,
                              void* d_out, int out_size, void* d_ws, size_t ws_size,
                              hipStream_t stream) {
    const float *x = nullptr, *Wqkv = nullptr, *Wproj = nullptr, *bproj = nullptr;
    for (int i = 0; i < n_in; ++i) {
        int sz = in_sizes[i];
        if      (sz == 2 * 2048 * 2048) x     = (const float*)d_in[i];
        else if (sz == 2048 * 6144)     Wqkv  = (const float*)d_in[i];
        else if (sz == 2048 * 2048)     Wproj = (const float*)d_in[i];
        else if (sz == 2048)            bproj = (const float*)d_in[i];
    }
    float* out = (float*)d_out;

    // ws overlay (all bf16); WprojT gets its own region (converted up front
    // by the fused convT2, while xb is still live for gemm_qkv).
    u16* xb     = (u16*)d_ws;
    u16* WqkvT  = xb    + (size_t)4096 * 2048;
    u16* Qb     = WqkvT + (size_t)6144 * 2048;
    u16* Kb     = Qb    + (size_t)32 * 2048 * 128;
    u16* VTb    = Kb    + (size_t)32 * 2048 * 128;
    u16* WprojT = VTb   + (size_t)32 * 2048 * 128;

    convx<<<dim3(4096), dim3(256), 0, stream>>>(x, xb);
    convT2<<<dim3(128, 32), dim3(256), 0, stream>>>(Wqkv, WqkvT, Wproj, WprojT);
    gemm_qkv<<<dim3(24, 32), dim3(512), 0, stream>>>(xb, WqkvT, Qb, Kb, VTb);
    attn_kern<<<dim3(16, 32), dim3(256), 0, stream>>>(Qb, Kb, VTb);
    gemm_proj<<<dim3(512), dim3(256), 0, stream>>>(Qb, WprojT, bproj, out);
}

// Round 9
// 368.749 us; speedup vs baseline: 1.0198x; 1.0198x over previous
//
#include <hip/hip_runtime.h>
#include <stdint.h>

typedef __attribute__((ext_vector_type(8))) short short8;
typedef __attribute__((ext_vector_type(4))) float f32x4;
typedef __attribute__((ext_vector_type(16))) float f32x16;
typedef __attribute__((ext_vector_type(4))) unsigned short u16x4;

typedef unsigned short u16;

constexpr int S_LEN = 2048;
constexpr int DH    = 128;

__device__ __forceinline__ u16 f2bf(float f) {
    union { float f; unsigned u; } v; v.f = f;
    unsigned r = v.u + 0x7FFFu + ((v.u >> 16) & 1u);
    return (u16)(r >> 16);
}
__device__ __forceinline__ unsigned cvt_pk_bf16(float lo, float hi) {
    unsigned r;
    asm("v_cvt_pk_bf16_f32 %0, %1, %2" : "=v"(r) : "v"(lo), "v"(hi));
    return r;
}
__device__ __forceinline__ void gl_lds16(const void* g, void* l) {
    __builtin_amdgcn_global_load_lds((const __attribute__((address_space(1))) void*)g,
                                     (__attribute__((address_space(3))) void*)l,
                                     16, 0, 0);
}

// ---------- fp32 -> bf16 bulk convert ----------
__global__ __launch_bounds__(256) void convx(const float* __restrict__ src,
                                             u16* __restrict__ dst) {
    size_t i = ((size_t)blockIdx.x * 256 + threadIdx.x) * 8;
    f32x4 a = *(const f32x4*)(src + i);
    f32x4 b = *(const f32x4*)(src + i + 4);
    short8 r;
    r[0] = (short)f2bf(a[0]); r[1] = (short)f2bf(a[1]);
    r[2] = (short)f2bf(a[2]); r[3] = (short)f2bf(a[3]);
    r[4] = (short)f2bf(b[0]); r[5] = (short)f2bf(b[1]);
    r[6] = (short)f2bf(b[2]); r[7] = (short)f2bf(b[3]);
    *(short8*)(dst + i) = r;
}

// ---------- fused transpose-convert for Wqkv AND Wproj (one dispatch) -------
__global__ __launch_bounds__(256) void convT2(const float* __restrict__ s1,
                                              u16* __restrict__ d1,
                                              const float* __restrict__ s2,
                                              u16* __restrict__ d2) {
    __shared__ u16 t[64][65];
    const int bx = blockIdx.x;
    const bool first = bx < 96;
    const float* src = first ? s1 : s2;
    u16* dst = first ? d1 : d2;
    const int cols = first ? 6144 : 2048;
    const int c0 = (first ? bx : bx - 96) * 64;
    const int r0 = blockIdx.y * 64;
    const int rows = 2048;
    const int tid = threadIdx.x;
    const int colq = (tid & 15) * 4;
    const int rw   = tid >> 4;
#pragma unroll
    for (int p = 0; p < 4; ++p) {
        int row = p * 16 + rw;
        f32x4 v = *(const f32x4*)(src + (size_t)(r0 + row) * cols + c0 + colq);
        t[colq + 0][row] = f2bf(v[0]);
        t[colq + 1][row] = f2bf(v[1]);
        t[colq + 2][row] = f2bf(v[2]);
        t[colq + 3][row] = f2bf(v[3]);
    }
    __syncthreads();
    const int rowq = (tid & 15) * 4;
    const int cw   = tid >> 4;
#pragma unroll
    for (int p = 0; p < 4; ++p) {
        int col = p * 16 + cw;
        u16x4 o;
        o[0] = t[col][rowq + 0]; o[1] = t[col][rowq + 1];
        o[2] = t[col][rowq + 2]; o[3] = t[col][rowq + 3];
        *(u16x4*)(dst + (size_t)(c0 + col) * rows + r0 + rowq) = o;
    }
}

// ================= QKV GEMM: 128x256 tile, BK=64, 8-wave, counted-vmcnt =====
// (round-3/5/7 verified: ~111us, MfmaUtil ~39%, 0 bank conflicts)
__global__ __launch_bounds__(512, 2) void gemm_qkv(
        const u16* __restrict__ A, const u16* __restrict__ BT,
        u16* __restrict__ Qo, u16* __restrict__ Ko, u16* __restrict__ VTo) {
    __shared__ __align__(16) u16 lA[2][128 * 64];   // 16KB x2
    __shared__ __align__(16) u16 lB[2][256 * 64];   // 32KB x2
    const int tid = threadIdx.x;
    const int lane = tid & 63, wave = tid >> 6;
    const int quad = lane >> 4, l16 = lane & 15;
    const int wr = wave >> 2, wc = wave & 3;
    const int m0 = blockIdx.y * 128, n0 = blockIdx.x * 256;
    const int sw = l16 & 7;                 // read-side swizzle key (== row&7)
    const int c4 = tid & 7;                 // stage chunk index
    f32x4 acc[4][4] = {};

    auto stageA = [&](int t1, int nb) {     // 128x64 tile, 2 loads/thread
#pragma unroll
        for (int j = 0; j < 2; ++j) {
            int idx = j * 512 + tid;
            int row = idx >> 3;
            gl_lds16(A + (size_t)(m0 + row) * 2048 + t1 * 64 + ((c4 ^ (row & 7)) * 8),
                     &lA[nb][row * 64 + c4 * 8]);
        }
    };
    auto stageB = [&](int h, int t1, int nb) {  // 128 rows (bit5==h), 2 loads
#pragma unroll
        for (int j = 0; j < 2; ++j) {
            int rih = (j * 512 + tid) >> 3;
            int row = (rih & 31) + h * 32 + (rih >> 5) * 64;
            gl_lds16(BT + (size_t)(n0 + row) * 2048 + t1 * 64 + ((c4 ^ (row & 7)) * 8),
                     &lB[nb][row * 64 + c4 * 8]);
        }
    };

    // prologue: tile 0 -> queue [A0:2, B0h0:2, B0h1:2]
    stageA(0, 0); stageB(0, 0, 0); stageB(1, 0, 0);

    constexpr int NT = 32;
    for (int t = 0; t < NT; ++t) {
        const int buf = t & 1, nb = buf ^ 1;
        const bool pf = (t + 1 < NT);
        // ---- W0: A(t), B-h0(t) landed everywhere ----
        asm volatile("s_waitcnt vmcnt(2)\n\ts_barrier" ::: "memory");
        // ---- R0: all A frags + B half0 frags ----
        short8 af[4][2], bf0[2][2];
        const int abase = (wr * 64 + l16) * 64;
        const int bbase = (wc * 64 + l16) * 64;
#pragma unroll
        for (int m = 0; m < 4; ++m)
#pragma unroll
            for (int ks = 0; ks < 2; ++ks)
                af[m][ks] = *(const short8*)&lA[buf][abase + m * 1024 + (((ks * 4 + quad) ^ sw)) * 8];
#pragma unroll
        for (int n = 0; n < 2; ++n)
#pragma unroll
            for (int ks = 0; ks < 2; ++ks)
                bf0[n][ks] = *(const short8*)&lB[buf][bbase + n * 1024 + (((ks * 4 + quad) ^ sw)) * 8];
        // ---- G0: stage A(t+1), B0(t+1) ----
        if (pf) { stageA(t + 1, nb); stageB(0, t + 1, nb); }
        // ---- M0: 16 MFMA (n-half 0) ----
        __builtin_amdgcn_s_setprio(1);
#pragma unroll
        for (int m = 0; m < 4; ++m)
#pragma unroll
            for (int n = 0; n < 2; ++n)
#pragma unroll
                for (int ks = 0; ks < 2; ++ks)
                    acc[m][n] = __builtin_amdgcn_mfma_f32_16x16x32_bf16(
                        af[m][ks], bf0[n][ks], acc[m][n], 0, 0, 0);
        __builtin_amdgcn_s_setprio(0);
        // ---- W1: B-h1(t) landed everywhere (keep t+1's 4 in flight) ----
        if (pf) asm volatile("s_waitcnt vmcnt(4)\n\ts_barrier" ::: "memory");
        else    asm volatile("s_waitcnt vmcnt(0)\n\ts_barrier" ::: "memory");
        // ---- R1: B half1 frags ----
        short8 bf1[2][2];
#pragma unroll
        for (int n = 0; n < 2; ++n)
#pragma unroll
            for (int ks = 0; ks < 2; ++ks)
                bf1[n][ks] = *(const short8*)&lB[buf][bbase + 2048 + n * 1024 + (((ks * 4 + quad) ^ sw)) * 8];
        // ---- G1: stage B1(t+1) ----
        if (pf) stageB(1, t + 1, nb);
        // ---- M1: 16 MFMA (n-half 1) ----
        __builtin_amdgcn_s_setprio(1);
#pragma unroll
        for (int m = 0; m < 4; ++m)
#pragma unroll
            for (int n = 0; n < 2; ++n)
#pragma unroll
                for (int ks = 0; ks < 2; ++ks)
                    acc[m][n + 2] = __builtin_amdgcn_mfma_f32_16x16x32_bf16(
                        af[m][ks], bf1[n][ks], acc[m][n + 2], 0, 0, 0);
        __builtin_amdgcn_s_setprio(0);
    }

    // ---- epilogue: split to Q / K / VT ----
#pragma unroll
    for (int m = 0; m < 4; ++m) {
        int r0r = m0 + wr * 64 + m * 16 + quad * 4;
        int b = r0r >> 11, s0 = r0r & 2047;
#pragma unroll
        for (int n = 0; n < 4; ++n) {
            int cc = n0 + wc * 64 + n * 16 + l16;
            int which = cc >> 11, hd = (cc >> 7) & 15, dh = cc & 127;
            if (which < 2) {
                u16* dst = which == 0 ? Qo : Ko;
#pragma unroll
                for (int rg = 0; rg < 4; ++rg)
                    dst[(size_t)((b * 16 + hd) * 2048 + s0 + rg) * 128 + dh] = f2bf(acc[m][n][rg]);
            } else {
                u16x4 v;
#pragma unroll
                for (int rg = 0; rg < 4; ++rg) v[rg] = f2bf(acc[m][n][rg]);
                *(u16x4*)&VTo[((size_t)(b * 16 + hd) * 128 + dh) * 2048 + s0] = v;
            }
        }
    }
}

// ================= flash attention (32x32 swapped-QK, counted-vmcnt) ========
// grid (32,16): bx = head, by -> qb via LPT map (by<8 -> 15-by else by-8).
// LPT's (i, i+256) co-residency gives qb pairs (15-by, by) -> CONSTANT 34
// iters/CU; makespan ~32.3 units, near the 32-unit bound (equal pairing
// measured +14us). O is written FLAT [b*2048+s][h*128+dh] to Ob (proj's A
// layout) -- kills proj's strided gather at zero cost here.
__global__ __launch_bounds__(256, 2) void attn_kern(
        const u16* __restrict__ Qp, const u16* __restrict__ Kp,
        const u16* __restrict__ VTp, u16* __restrict__ Ob) {
    __shared__ __align__(16) u16 lK[2][64 * 128];   // 16KB x2
    __shared__ __align__(16) u16 lV[2][128 * 64];   // 16KB x2
    const int tid = threadIdx.x, lane = tid & 63, wave = tid >> 6;
    const int ql = lane & 31, hi = lane >> 5;
    const int qb = (blockIdx.y < 8) ? (15 - (int)blockIdx.y) : ((int)blockIdx.y - 8);
    const int bh = blockIdx.x;
    const int qbase = qb * 128 + wave * 32;
    const int qmax = qbase + 31;
    const int nkt = 2 * qb + 2;
    const u16* Qh = Qp + (size_t)bh * S_LEN * DH;
    const u16* Kh = Kp + (size_t)bh * S_LEN * DH;
    const u16* VTh = VTp + (size_t)bh * DH * S_LEN;

    // Q fragments (B-operand): lane holds q = qbase+ql, d = c*16 + hi*8 + j
    short8 qf[8];
#pragma unroll
    for (int c = 0; c < 8; ++c)
        qf[c] = *(const short8*)&Qh[(size_t)(qbase + ql) * 128 + c * 16 + hi * 8];

    f32x16 acc[4] = {};           // O: col d = dc*32+ql, rows q via reg index
    float mrun = -1e30f, lrun = 0.f;
    const float SC = 0.08838834764831845f * 1.44269504088896f; // scale*log2(e)

    auto stageK = [&](int kt, int b) {
        const u16* ks = Kh + (size_t)kt * 64 * 128;
#pragma unroll
        for (int p = 0; p < 4; ++p) {
            int slot = p * 256 + tid;
            int row = slot >> 4, c4 = slot & 15;
            gl_lds16(ks + row * 128 + ((c4 ^ (row & 15)) * 8), &lK[b][slot * 8]);
        }
    };
    auto stageV = [&](int kt, int b) {
        const u16* vs = VTh + kt * 64;
#pragma unroll
        for (int p = 0; p < 4; ++p) {
            int slot = p * 256 + tid;
            int row = slot >> 3, c4 = slot & 7;
            gl_lds16(vs + (size_t)row * 2048 + ((c4 ^ (row & 7)) * 8), &lV[b][slot * 8]);
        }
    };

    // prologue: K0 ready, V0:4 in flight
    stageK(0, 0);
    stageV(0, 0);
    asm volatile("s_waitcnt vmcnt(4)\n\ts_barrier" ::: "memory");

    for (int kt = 0; kt < nkt; ++kt) {
        const int buf = kt & 1;
        const bool more = kt + 1 < nkt;
        const bool compute = (kt * 64 <= qmax);   // wave-uniform causal skip
        float pv0[16], pv1[16];
        if (compute) {
            const bool part = (kt * 64 + 63 > qbase);
            // ---- QK^T swapped: D[k][q], two 32x32 tiles over KVBLK=64 ----
            f32x16 s0 = {}, s1 = {};
            __builtin_amdgcn_s_setprio(1);
#pragma unroll
            for (int c = 0; c < 8; ++c) {
                int sl = ((c * 2 + hi) ^ (ql & 15)) * 8;   // (32+ql)&15 == ql&15
                short8 k0 = *(const short8*)&lK[buf][ql * 128 + sl];
                short8 k1 = *(const short8*)&lK[buf][(32 + ql) * 128 + sl];
                s0 = __builtin_amdgcn_mfma_f32_32x32x16_bf16(k0, qf[c], s0, 0, 0, 0);
                s1 = __builtin_amdgcn_mfma_f32_32x32x16_bf16(k1, qf[c], s1, 0, 0, 0);
            }
            __builtin_amdgcn_s_setprio(0);
            // issue next K early: latency hides under softmax VALU below
            if (more) stageK(kt + 1, buf ^ 1);
            // ---- scale + (hoisted) causal mask + row max ----
            float pm = -1e30f;
            const int qg = qbase + ql;
            if (part) {
#pragma unroll
                for (int r = 0; r < 16; ++r) {
                    int krow = (r & 3) + 8 * (r >> 2) + 4 * hi;
                    float a = s0[r] * SC;
                    float b = s1[r] * SC;
                    if (kt * 64 + krow > qg)      a = -1e30f;
                    if (kt * 64 + 32 + krow > qg) b = -1e30f;
                    pv0[r] = a; pv1[r] = b;
                    pm = fmaxf(pm, fmaxf(a, b));
                }
            } else {
#pragma unroll
                for (int r = 0; r < 16; ++r) {
                    float a = s0[r] * SC;
                    float b = s1[r] * SC;
                    pv0[r] = a; pv1[r] = b;
                    pm = fmaxf(pm, fmaxf(a, b));
                }
            }
            pm = fmaxf(pm, __shfl_xor(pm, 32));
            // ---- defer-max rescale (rare) ----
            if (__any(pm - mrun > 8.f)) {
                float mn = fmaxf(mrun, pm);
                float al = exp2f(mrun - mn);
                mrun = mn;
                lrun *= al;
#pragma unroll
                for (int r = 0; r < 16; ++r) {
                    float ar = __shfl(al, (r & 3) + 8 * (r >> 2) + 4 * hi);
#pragma unroll
                    for (int dc = 0; dc < 4; ++dc)
                        acc[dc][r] *= ar;
                }
            }
            // ---- exp2 + row sum ----
            float rs = 0.f;
#pragma unroll
            for (int r = 0; r < 16; ++r) {
                pv0[r] = exp2f(pv0[r] - mrun);
                pv1[r] = exp2f(pv1[r] - mrun);
                rs += pv0[r] + pv1[r];
            }
            rs += __shfl_xor(rs, 32);
            lrun += rs;
        } else if (more) {
            stageK(kt + 1, buf ^ 1);
        }
        // ---- mid barrier: V(kt) landed everywhere; K(kt+1) stays in flight
        if (more) asm volatile("s_waitcnt vmcnt(4)\n\ts_barrier" ::: "memory");
        else      asm volatile("s_waitcnt vmcnt(0)\n\ts_barrier" ::: "memory");
        if (compute) {
            // ---- in-register P -> A-fragment repack (cvt_pk: 1 instr / pair)
            unsigned X0[8], X1[8];
#pragma unroll
            for (int i = 0; i < 8; ++i) {
                X0[i] = cvt_pk_bf16(pv0[2 * i], pv0[2 * i + 1]);
                X1[i] = cvt_pk_bf16(pv1[2 * i], pv1[2 * i + 1]);
            }
            short8 pa[4];
#pragma unroll
            for (int t = 0; t < 2; ++t)
#pragma unroll
                for (int h = 0; h < 2; ++h) {
                    unsigned x0 = t ? X1[4 * h + 0] : X0[4 * h + 0];
                    unsigned x1 = t ? X1[4 * h + 1] : X0[4 * h + 1];
                    unsigned x2 = t ? X1[4 * h + 2] : X0[4 * h + 2];
                    unsigned x3 = t ? X1[4 * h + 3] : X0[4 * h + 3];
                    unsigned sx0 = (unsigned)__shfl_xor((int)x0, 32);
                    unsigned sx1 = (unsigned)__shfl_xor((int)x1, 32);
                    unsigned sx2 = (unsigned)__shfl_xor((int)x2, 32);
                    unsigned sx3 = (unsigned)__shfl_xor((int)x3, 32);
                    union { unsigned u[4]; short8 s; } uf;
                    uf.u[0] = hi ? sx2 : x0;
                    uf.u[1] = hi ? sx3 : x1;
                    uf.u[2] = hi ? x2 : sx0;
                    uf.u[3] = hi ? x3 : sx1;
                    pa[t * 2 + h] = uf.s;
                }
            // ---- PV: O[q][d] += P[q][k] V[k][d] ----
            __builtin_amdgcn_s_setprio(1);
#pragma unroll
            for (int dc = 0; dc < 4; ++dc) {
                const int rv = dc * 32 + ql;
#pragma unroll
                for (int kc = 0; kc < 4; ++kc) {
                    short8 vf = *(const short8*)&lV[buf][rv * 64 + (((kc * 2 + hi) ^ (ql & 7)) * 8)];
                    acc[dc] = __builtin_amdgcn_mfma_f32_32x32x16_bf16(pa[kc], vf, acc[dc], 0, 0, 0);
                }
            }
            __builtin_amdgcn_s_setprio(0);
        }
        if (more) {
            stageV(kt + 1, buf ^ 1);
            // end barrier: K(kt+1) landed everywhere; V(kt+1) stays in flight
            asm volatile("s_waitcnt vmcnt(4)\n\ts_barrier" ::: "memory");
        }
    }

    // ---- epilogue: normalize and store FLAT [b*2048+s][h*128+d] ----
    const int bb = bh >> 4, hh = bh & 15;
    u16* Oh = Ob + (size_t)bb * 2048 * 2048 + (size_t)hh * 128;
    float linv = 1.f / lrun;
#pragma unroll
    for (int r = 0; r < 16; ++r) {
        int qr = (r & 3) + 8 * (r >> 2) + 4 * hi;
        float lr = __shfl(linv, qr);
        int qq = qbase + qr;
#pragma unroll
        for (int dc = 0; dc < 4; ++dc)
            Oh[(size_t)qq * 2048 + dc * 32 + ql] = f2bf(acc[dc][r] * lr);
    }
}

// ================= proj GEMM: 128x128 tile, 4-wave, 2 blocks/CU =============
// A now reads the FLAT attn output Ob [4096][2048] -- linear staging exactly
// like gemm_qkv's A (the old head-interleaved gather was 16B @ 256B stride:
// 8x line over-fetch, ~330 TF). Everything else: round-5 verified template.
__global__ __launch_bounds__(256, 2) void gemm_proj(
        const u16* __restrict__ Ob, const u16* __restrict__ BT,
        const float* __restrict__ bias, float* __restrict__ out) {
    __shared__ __align__(16) u16 lA[2][128 * 64];   // 16KB x2
    __shared__ __align__(16) u16 lB[2][128 * 64];   // 16KB x2
    const int tid = threadIdx.x;
    const int lane = tid & 63, wave = tid >> 6;
    const int quad = lane >> 4, l16 = lane & 15;
    const int wm = wave >> 1, wn = wave & 1;
    const int bid = blockIdx.x;
    const int swz = (bid & 7) * 64 + (bid >> 3);     // XCD-chunked remap
    const int m0 = (swz >> 4) * 128, n0 = (swz & 15) * 128;
    const int sw = l16 & 7;
    const int c4 = tid & 7;
    f32x4 acc[4][4] = {};

    auto stageA = [&](int t1, int nb) {     // 128x64 from Ob, 4 loads/thread
#pragma unroll
        for (int j = 0; j < 4; ++j) {
            int row = (j * 256 + tid) >> 3;
            gl_lds16(Ob + (size_t)(m0 + row) * 2048 + t1 * 64 + ((c4 ^ (row & 7)) * 8),
                     &lA[nb][row * 64 + c4 * 8]);
        }
    };
    auto stageB = [&](int h, int t1, int nb) {  // 64 rows (bit5==h), 2 loads
#pragma unroll
        for (int j = 0; j < 2; ++j) {
            int rih = (j * 256 + tid) >> 3;
            int row = (rih & 31) + h * 32 + (rih >> 5) * 64;
            gl_lds16(BT + (size_t)(n0 + row) * 2048 + t1 * 64 + ((c4 ^ (row & 7)) * 8),
                     &lB[nb][row * 64 + c4 * 8]);
        }
    };

    // prologue: FIFO [B0:2][A:4][B1:2]
    stageB(0, 0, 0);
    asm volatile("" ::: "memory");
    stageA(0, 0);
    asm volatile("" ::: "memory");
    stageB(1, 0, 0);

    constexpr int NT = 32;
    for (int t = 0; t < NT; ++t) {
        const int buf = t & 1, nb = buf ^ 1;
        const bool pf = (t + 1 < NT);
        // W0: B0(t)+A(t) landed (B1(t):2 stay in flight)
        asm volatile("s_waitcnt vmcnt(2)\n\ts_barrier" ::: "memory");
        short8 af[4][2], bf0[2][2];
        const int abase = (wm * 64 + l16) * 64;
        const int bbase = (wn * 64 + l16) * 64;
#pragma unroll
        for (int m = 0; m < 4; ++m)
#pragma unroll
            for (int ks = 0; ks < 2; ++ks)
                af[m][ks] = *(const short8*)&lA[buf][abase + m * 1024 + (((ks * 4 + quad) ^ sw)) * 8];
#pragma unroll
        for (int n = 0; n < 2; ++n)
#pragma unroll
            for (int ks = 0; ks < 2; ++ks)
                bf0[n][ks] = *(const short8*)&lB[buf][bbase + n * 1024 + (((ks * 4 + quad) ^ sw)) * 8];
        if (pf) {
            stageB(0, t + 1, nb);
            asm volatile("" ::: "memory");
            stageA(t + 1, nb);
        }
        __builtin_amdgcn_s_setprio(1);
#pragma unroll
        for (int m = 0; m < 4; ++m)
#pragma unroll
            for (int n = 0; n < 2; ++n)
#pragma unroll
                for (int ks = 0; ks < 2; ++ks)
                    acc[m][n] = __builtin_amdgcn_mfma_f32_16x16x32_bf16(
                        af[m][ks], bf0[n][ks], acc[m][n], 0, 0, 0);
        __builtin_amdgcn_s_setprio(0);
        // W1: B1(t) landed (t+1's B0:2 + A:4 = 6 stay in flight)
        if (pf) asm volatile("s_waitcnt vmcnt(6)\n\ts_barrier" ::: "memory");
        else    asm volatile("s_waitcnt vmcnt(0)\n\ts_barrier" ::: "memory");
        short8 bf1[2][2];
#pragma unroll
        for (int n = 0; n < 2; ++n)
#pragma unroll
            for (int ks = 0; ks < 2; ++ks)
                bf1[n][ks] = *(const short8*)&lB[buf][bbase + 2048 + n * 1024 + (((ks * 4 + quad) ^ sw)) * 8];
        if (pf) stageB(1, t + 1, nb);
        __builtin_amdgcn_s_setprio(1);
#pragma unroll
        for (int m = 0; m < 4; ++m)
#pragma unroll
            for (int n = 0; n < 2; ++n)
#pragma unroll
                for (int ks = 0; ks < 2; ++ks)
                    acc[m][n + 2] = __builtin_amdgcn_mfma_f32_16x16x32_bf16(
                        af[m][ks], bf1[n][ks], acc[m][n + 2], 0, 0, 0);
        __builtin_amdgcn_s_setprio(0);
    }

    // ---- epilogue: fp32 + bias ----
#pragma unroll
    for (int m = 0; m < 4; ++m) {
        int r0r = m0 + wm * 64 + m * 16 + quad * 4;
#pragma unroll
        for (int n = 0; n < 4; ++n) {
            int cc = n0 + wn * 64 + n * 16 + l16;
            float bv = bias[cc];
#pragma unroll
            for (int rg = 0; rg < 4; ++rg)
                out[(size_t)(r0r + rg) * 2048 + cc] = acc[m][n][rg] + bv;
        }
    }
}

extern "C" void kernel_launch(void* const* d_in, const int* in_sizes, int n_in,
                              void* d_out, int out_size, void* d_ws, size_t ws_size,
                              hipStream_t stream) {
    const float *x = nullptr, *Wqkv = nullptr, *Wproj = nullptr, *bproj = nullptr;
    for (int i = 0; i < n_in; ++i) {
        int sz = in_sizes[i];
        if      (sz == 2 * 2048 * 2048) x     = (const float*)d_in[i];
        else if (sz == 2048 * 6144)     Wqkv  = (const float*)d_in[i];
        else if (sz == 2048 * 2048)     Wproj = (const float*)d_in[i];
        else if (sz == 2048)            bproj = (const float*)d_in[i];
    }
    float* out = (float*)d_out;

    // ws overlay (all bf16). Ob (flat attn output, 4096x2048) reuses xb's
    // region: x is consumed by gemm_qkv before attn_kern writes Ob.
    u16* xb     = (u16*)d_ws;
    u16* WqkvT  = xb    + (size_t)4096 * 2048;
    u16* Qb     = WqkvT + (size_t)6144 * 2048;
    u16* Kb     = Qb    + (size_t)32 * 2048 * 128;
    u16* VTb    = Kb    + (size_t)32 * 2048 * 128;
    u16* WprojT = VTb   + (size_t)32 * 2048 * 128;
    u16* Obuf   = xb;   // overlay: xb dead after gemm_qkv

    convx<<<dim3(4096), dim3(256), 0, stream>>>(x, xb);
    convT2<<<dim3(128, 32), dim3(256), 0, stream>>>(Wqkv, WqkvT, Wproj, WprojT);
    gemm_qkv<<<dim3(24, 32), dim3(512), 0, stream>>>(xb, WqkvT, Qb, Kb, VTb);
    attn_kern<<<dim3(32, 16), dim3(256), 0, stream>>>(Qb, Kb, VTb, Obuf);
    gemm_proj<<<dim3(512), dim3(256), 0, stream>>>(Obuf, WprojT, bproj, out);
}

// Round 10
// 363.444 us; speedup vs baseline: 1.0347x; 1.0146x over previous
//
#include <hip/hip_runtime.h>
#include <stdint.h>

typedef __attribute__((ext_vector_type(8))) short short8;
typedef __attribute__((ext_vector_type(4))) float f32x4;
typedef __attribute__((ext_vector_type(16))) float f32x16;
typedef __attribute__((ext_vector_type(4))) unsigned short u16x4;

typedef unsigned short u16;

constexpr int S_LEN = 2048;
constexpr int DH    = 128;

__device__ __forceinline__ u16 f2bf(float f) {
    union { float f; unsigned u; } v; v.f = f;
    unsigned r = v.u + 0x7FFFu + ((v.u >> 16) & 1u);
    return (u16)(r >> 16);
}
__device__ __forceinline__ unsigned cvt_pk_bf16(float lo, float hi) {
    unsigned r;
    asm("v_cvt_pk_bf16_f32 %0, %1, %2" : "=v"(r) : "v"(lo), "v"(hi));
    return r;
}
__device__ __forceinline__ void gl_lds16(const void* g, void* l) {
    __builtin_amdgcn_global_load_lds((const __attribute__((address_space(1))) void*)g,
                                     (__attribute__((address_space(3))) void*)l,
                                     16, 0, 0);
}

// ---------- fp32 -> bf16 bulk convert ----------
__global__ __launch_bounds__(256) void convx(const float* __restrict__ src,
                                             u16* __restrict__ dst) {
    size_t i = ((size_t)blockIdx.x * 256 + threadIdx.x) * 8;
    f32x4 a = *(const f32x4*)(src + i);
    f32x4 b = *(const f32x4*)(src + i + 4);
    short8 r;
    r[0] = (short)f2bf(a[0]); r[1] = (short)f2bf(a[1]);
    r[2] = (short)f2bf(a[2]); r[3] = (short)f2bf(a[3]);
    r[4] = (short)f2bf(b[0]); r[5] = (short)f2bf(b[1]);
    r[6] = (short)f2bf(b[2]); r[7] = (short)f2bf(b[3]);
    *(short8*)(dst + i) = r;
}

// ---------- fused transpose-convert for Wqkv AND Wproj (one dispatch) -------
__global__ __launch_bounds__(256) void convT2(const float* __restrict__ s1,
                                              u16* __restrict__ d1,
                                              const float* __restrict__ s2,
                                              u16* __restrict__ d2) {
    __shared__ u16 t[64][65];
    const int bx = blockIdx.x;
    const bool first = bx < 96;
    const float* src = first ? s1 : s2;
    u16* dst = first ? d1 : d2;
    const int cols = first ? 6144 : 2048;
    const int c0 = (first ? bx : bx - 96) * 64;
    const int r0 = blockIdx.y * 64;
    const int rows = 2048;
    const int tid = threadIdx.x;
    const int colq = (tid & 15) * 4;
    const int rw   = tid >> 4;
#pragma unroll
    for (int p = 0; p < 4; ++p) {
        int row = p * 16 + rw;
        f32x4 v = *(const f32x4*)(src + (size_t)(r0 + row) * cols + c0 + colq);
        t[colq + 0][row] = f2bf(v[0]);
        t[colq + 1][row] = f2bf(v[1]);
        t[colq + 2][row] = f2bf(v[2]);
        t[colq + 3][row] = f2bf(v[3]);
    }
    __syncthreads();
    const int rowq = (tid & 15) * 4;
    const int cw   = tid >> 4;
#pragma unroll
    for (int p = 0; p < 4; ++p) {
        int col = p * 16 + cw;
        u16x4 o;
        o[0] = t[col][rowq + 0]; o[1] = t[col][rowq + 1];
        o[2] = t[col][rowq + 2]; o[3] = t[col][rowq + 3];
        *(u16x4*)(dst + (size_t)(c0 + col) * rows + r0 + rowq) = o;
    }
}

// ================= QKV GEMM: 128x256, BK=64, TRIPLE-buffer 2-ahead prefetch =
// Round-9 counters: MfmaUtil 39 + VALU 24 = 63% busy, HBM 12%, conflicts 0,
// 1 block/CU -> the 37% idle is EXPOSED LOAD LATENCY: A(t),B0(t) issued at
// G0(t-1), awaited ~200cyc later at W0(t) vs ~500-900cyc HBM/L2 latency.
// Fix: 3 LDS buffers (144KB <= 160KB, still 1 block/CU -> no occupancy cost),
// prefetch tile t+2 -> issue-to-wait distance ~1.5 tiles (~500cyc).
// Per-thread FIFO (G0={A,B0}:4 loads, G1={B1}:2; prologue tiles 0,1 = 12):
//   steady: W0 vmcnt(8) lands A(t),B0(t); W1 vmcnt(10) lands B1(t)
//   drain:  t=NT-2: W1 vmcnt(6); t=NT-1: W0 vmcnt(2), W1 vmcnt(0)
// Buffer safety: G0(t) writes buf (t+2)%3==(t-1)%3 whose last reads R1(t-1)
// complete before the W0(t) barrier that precedes G0(t) in program order.
__global__ __launch_bounds__(512, 2) void gemm_qkv(
        const u16* __restrict__ A, const u16* __restrict__ BT,
        u16* __restrict__ Qo, u16* __restrict__ Ko, u16* __restrict__ VTo) {
    __shared__ __align__(16) u16 lA[3][128 * 64];   // 16KB x3
    __shared__ __align__(16) u16 lB[3][256 * 64];   // 32KB x3
    const int tid = threadIdx.x;
    const int lane = tid & 63, wave = tid >> 6;
    const int quad = lane >> 4, l16 = lane & 15;
    const int wr = wave >> 2, wc = wave & 3;
    const int m0 = blockIdx.y * 128, n0 = blockIdx.x * 256;
    const int sw = l16 & 7;                 // read-side swizzle key (== row&7)
    const int c4 = tid & 7;                 // stage chunk index
    f32x4 acc[4][4] = {};

    auto stageA = [&](int t1, int nb) {     // 128x64 tile, 2 loads/thread
#pragma unroll
        for (int j = 0; j < 2; ++j) {
            int idx = j * 512 + tid;
            int row = idx >> 3;
            gl_lds16(A + (size_t)(m0 + row) * 2048 + t1 * 64 + ((c4 ^ (row & 7)) * 8),
                     &lA[nb][row * 64 + c4 * 8]);
        }
    };
    auto stageB = [&](int h, int t1, int nb) {  // 128 rows (bit5==h), 2 loads
#pragma unroll
        for (int j = 0; j < 2; ++j) {
            int rih = (j * 512 + tid) >> 3;
            int row = (rih & 31) + h * 32 + (rih >> 5) * 64;
            gl_lds16(BT + (size_t)(n0 + row) * 2048 + t1 * 64 + ((c4 ^ (row & 7)) * 8),
                     &lB[nb][row * 64 + c4 * 8]);
        }
    };

    // prologue: tiles 0 and 1 -> FIFO [A0 B00 B10 A1 B01 B11] = 12 loads
    stageA(0, 0); stageB(0, 0, 0); stageB(1, 0, 0);
    stageA(1, 1); stageB(0, 1, 1); stageB(1, 1, 1);

    constexpr int NT = 32;
    int buf = 0, nb2 = 2;                    // t%3 and (t+2)%3, rotated
    for (int t = 0; t < NT; ++t) {
        const bool pf = (t + 2 < NT);
        // ---- W0: A(t), B-h0(t) landed everywhere ----
        if (t < NT - 1) asm volatile("s_waitcnt vmcnt(8)\n\ts_barrier" ::: "memory");
        else            asm volatile("s_waitcnt vmcnt(2)\n\ts_barrier" ::: "memory");
        // ---- R0: all A frags + B half0 frags ----
        short8 af[4][2], bf0[2][2];
        const int abase = (wr * 64 + l16) * 64;
        const int bbase = (wc * 64 + l16) * 64;
#pragma unroll
        for (int m = 0; m < 4; ++m)
#pragma unroll
            for (int ks = 0; ks < 2; ++ks)
                af[m][ks] = *(const short8*)&lA[buf][abase + m * 1024 + (((ks * 4 + quad) ^ sw)) * 8];
#pragma unroll
        for (int n = 0; n < 2; ++n)
#pragma unroll
            for (int ks = 0; ks < 2; ++ks)
                bf0[n][ks] = *(const short8*)&lB[buf][bbase + n * 1024 + (((ks * 4 + quad) ^ sw)) * 8];
        // ---- G0: stage A(t+2), B0(t+2) two tiles ahead ----
        if (pf) { stageA(t + 2, nb2); stageB(0, t + 2, nb2); }
        // ---- M0: 16 MFMA (n-half 0) ----
        __builtin_amdgcn_s_setprio(1);
#pragma unroll
        for (int m = 0; m < 4; ++m)
#pragma unroll
            for (int n = 0; n < 2; ++n)
#pragma unroll
                for (int ks = 0; ks < 2; ++ks)
                    acc[m][n] = __builtin_amdgcn_mfma_f32_16x16x32_bf16(
                        af[m][ks], bf0[n][ks], acc[m][n], 0, 0, 0);
        __builtin_amdgcn_s_setprio(0);
        // ---- W1: B-h1(t) landed everywhere ----
        if (t < NT - 2)      asm volatile("s_waitcnt vmcnt(10)\n\ts_barrier" ::: "memory");
        else if (t == NT - 2) asm volatile("s_waitcnt vmcnt(6)\n\ts_barrier" ::: "memory");
        else                 asm volatile("s_waitcnt vmcnt(0)\n\ts_barrier" ::: "memory");
        // ---- R1: B half1 frags ----
        short8 bf1[2][2];
#pragma unroll
        for (int n = 0; n < 2; ++n)
#pragma unroll
            for (int ks = 0; ks < 2; ++ks)
                bf1[n][ks] = *(const short8*)&lB[buf][bbase + 2048 + n * 1024 + (((ks * 4 + quad) ^ sw)) * 8];
        // ---- G1: stage B1(t+2) ----
        if (pf) stageB(1, t + 2, nb2);
        // ---- M1: 16 MFMA (n-half 1) ----
        __builtin_amdgcn_s_setprio(1);
#pragma unroll
        for (int m = 0; m < 4; ++m)
#pragma unroll
            for (int n = 0; n < 2; ++n)
#pragma unroll
                for (int ks = 0; ks < 2; ++ks)
                    acc[m][n + 2] = __builtin_amdgcn_mfma_f32_16x16x32_bf16(
                        af[m][ks], bf1[n][ks], acc[m][n + 2], 0, 0, 0);
        __builtin_amdgcn_s_setprio(0);
        // rotate buffer indices (t%3, (t+2)%3)
        buf = (buf == 2) ? 0 : buf + 1;
        nb2 = (nb2 == 2) ? 0 : nb2 + 1;
    }

    // ---- epilogue: split to Q / K / VT ----
#pragma unroll
    for (int m = 0; m < 4; ++m) {
        int r0r = m0 + wr * 64 + m * 16 + quad * 4;
        int b = r0r >> 11, s0 = r0r & 2047;
#pragma unroll
        for (int n = 0; n < 4; ++n) {
            int cc = n0 + wc * 64 + n * 16 + l16;
            int which = cc >> 11, hd = (cc >> 7) & 15, dh = cc & 127;
            if (which < 2) {
                u16* dst = which == 0 ? Qo : Ko;
#pragma unroll
                for (int rg = 0; rg < 4; ++rg)
                    dst[(size_t)((b * 16 + hd) * 2048 + s0 + rg) * 128 + dh] = f2bf(acc[m][n][rg]);
            } else {
                u16x4 v;
#pragma unroll
                for (int rg = 0; rg < 4; ++rg) v[rg] = f2bf(acc[m][n][rg]);
                *(u16x4*)&VTo[((size_t)(b * 16 + hd) * 128 + dh) * 2048 + s0] = v;
            }
        }
    }
}

// ================= flash attention (32x32 swapped-QK, counted-vmcnt) ========
// (round-9 state, kept byte-identical)
__global__ __launch_bounds__(256, 2) void attn_kern(
        const u16* __restrict__ Qp, const u16* __restrict__ Kp,
        const u16* __restrict__ VTp, u16* __restrict__ Ob) {
    __shared__ __align__(16) u16 lK[2][64 * 128];   // 16KB x2
    __shared__ __align__(16) u16 lV[2][128 * 64];   // 16KB x2
    const int tid = threadIdx.x, lane = tid & 63, wave = tid >> 6;
    const int ql = lane & 31, hi = lane >> 5;
    const int qb = (blockIdx.y < 8) ? (15 - (int)blockIdx.y) : ((int)blockIdx.y - 8);
    const int bh = blockIdx.x;
    const int qbase = qb * 128 + wave * 32;
    const int qmax = qbase + 31;
    const int nkt = 2 * qb + 2;
    const u16* Qh = Qp + (size_t)bh * S_LEN * DH;
    const u16* Kh = Kp + (size_t)bh * S_LEN * DH;
    const u16* VTh = VTp + (size_t)bh * DH * S_LEN;

    short8 qf[8];
#pragma unroll
    for (int c = 0; c < 8; ++c)
        qf[c] = *(const short8*)&Qh[(size_t)(qbase + ql) * 128 + c * 16 + hi * 8];

    f32x16 acc[4] = {};
    float mrun = -1e30f, lrun = 0.f;
    const float SC = 0.08838834764831845f * 1.44269504088896f; // scale*log2(e)

    auto stageK = [&](int kt, int b) {
        const u16* ks = Kh + (size_t)kt * 64 * 128;
#pragma unroll
        for (int p = 0; p < 4; ++p) {
            int slot = p * 256 + tid;
            int row = slot >> 4, c4 = slot & 15;
            gl_lds16(ks + row * 128 + ((c4 ^ (row & 15)) * 8), &lK[b][slot * 8]);
        }
    };
    auto stageV = [&](int kt, int b) {
        const u16* vs = VTh + kt * 64;
#pragma unroll
        for (int p = 0; p < 4; ++p) {
            int slot = p * 256 + tid;
            int row = slot >> 3, c4 = slot & 7;
            gl_lds16(vs + (size_t)row * 2048 + ((c4 ^ (row & 7)) * 8), &lV[b][slot * 8]);
        }
    };

    stageK(0, 0);
    stageV(0, 0);
    asm volatile("s_waitcnt vmcnt(4)\n\ts_barrier" ::: "memory");

    for (int kt = 0; kt < nkt; ++kt) {
        const int buf = kt & 1;
        const bool more = kt + 1 < nkt;
        const bool compute = (kt * 64 <= qmax);
        float pv0[16], pv1[16];
        if (compute) {
            const bool part = (kt * 64 + 63 > qbase);
            f32x16 s0 = {}, s1 = {};
            __builtin_amdgcn_s_setprio(1);
#pragma unroll
            for (int c = 0; c < 8; ++c) {
                int sl = ((c * 2 + hi) ^ (ql & 15)) * 8;
                short8 k0 = *(const short8*)&lK[buf][ql * 128 + sl];
                short8 k1 = *(const short8*)&lK[buf][(32 + ql) * 128 + sl];
                s0 = __builtin_amdgcn_mfma_f32_32x32x16_bf16(k0, qf[c], s0, 0, 0, 0);
                s1 = __builtin_amdgcn_mfma_f32_32x32x16_bf16(k1, qf[c], s1, 0, 0, 0);
            }
            __builtin_amdgcn_s_setprio(0);
            if (more) stageK(kt + 1, buf ^ 1);
            float pm = -1e30f;
            const int qg = qbase + ql;
            if (part) {
#pragma unroll
                for (int r = 0; r < 16; ++r) {
                    int krow = (r & 3) + 8 * (r >> 2) + 4 * hi;
                    float a = s0[r] * SC;
                    float b = s1[r] * SC;
                    if (kt * 64 + krow > qg)      a = -1e30f;
                    if (kt * 64 + 32 + krow > qg) b = -1e30f;
                    pv0[r] = a; pv1[r] = b;
                    pm = fmaxf(pm, fmaxf(a, b));
                }
            } else {
#pragma unroll
                for (int r = 0; r < 16; ++r) {
                    float a = s0[r] * SC;
                    float b = s1[r] * SC;
                    pv0[r] = a; pv1[r] = b;
                    pm = fmaxf(pm, fmaxf(a, b));
                }
            }
            pm = fmaxf(pm, __shfl_xor(pm, 32));
            if (__any(pm - mrun > 8.f)) {
                float mn = fmaxf(mrun, pm);
                float al = exp2f(mrun - mn);
                mrun = mn;
                lrun *= al;
#pragma unroll
                for (int r = 0; r < 16; ++r) {
                    float ar = __shfl(al, (r & 3) + 8 * (r >> 2) + 4 * hi);
#pragma unroll
                    for (int dc = 0; dc < 4; ++dc)
                        acc[dc][r] *= ar;
                }
            }
            float rs = 0.f;
#pragma unroll
            for (int r = 0; r < 16; ++r) {
                pv0[r] = exp2f(pv0[r] - mrun);
                pv1[r] = exp2f(pv1[r] - mrun);
                rs += pv0[r] + pv1[r];
            }
            rs += __shfl_xor(rs, 32);
            lrun += rs;
        } else if (more) {
            stageK(kt + 1, buf ^ 1);
        }
        if (more) asm volatile("s_waitcnt vmcnt(4)\n\ts_barrier" ::: "memory");
        else      asm volatile("s_waitcnt vmcnt(0)\n\ts_barrier" ::: "memory");
        if (compute) {
            unsigned X0[8], X1[8];
#pragma unroll
            for (int i = 0; i < 8; ++i) {
                X0[i] = cvt_pk_bf16(pv0[2 * i], pv0[2 * i + 1]);
                X1[i] = cvt_pk_bf16(pv1[2 * i], pv1[2 * i + 1]);
            }
            short8 pa[4];
#pragma unroll
            for (int t = 0; t < 2; ++t)
#pragma unroll
                for (int h = 0; h < 2; ++h) {
                    unsigned x0 = t ? X1[4 * h + 0] : X0[4 * h + 0];
                    unsigned x1 = t ? X1[4 * h + 1] : X0[4 * h + 1];
                    unsigned x2 = t ? X1[4 * h + 2] : X0[4 * h + 2];
                    unsigned x3 = t ? X1[4 * h + 3] : X0[4 * h + 3];
                    unsigned sx0 = (unsigned)__shfl_xor((int)x0, 32);
                    unsigned sx1 = (unsigned)__shfl_xor((int)x1, 32);
                    unsigned sx2 = (unsigned)__shfl_xor((int)x2, 32);
                    unsigned sx3 = (unsigned)__shfl_xor((int)x3, 32);
                    union { unsigned u[4]; short8 s; } uf;
                    uf.u[0] = hi ? sx2 : x0;
                    uf.u[1] = hi ? sx3 : x1;
                    uf.u[2] = hi ? x2 : sx0;
                    uf.u[3] = hi ? x3 : sx1;
                    pa[t * 2 + h] = uf.s;
                }
            __builtin_amdgcn_s_setprio(1);
#pragma unroll
            for (int dc = 0; dc < 4; ++dc) {
                const int rv = dc * 32 + ql;
#pragma unroll
                for (int kc = 0; kc < 4; ++kc) {
                    short8 vf = *(const short8*)&lV[buf][rv * 64 + (((kc * 2 + hi) ^ (ql & 7)) * 8)];
                    acc[dc] = __builtin_amdgcn_mfma_f32_32x32x16_bf16(pa[kc], vf, acc[dc], 0, 0, 0);
                }
            }
            __builtin_amdgcn_s_setprio(0);
        }
        if (more) {
            stageV(kt + 1, buf ^ 1);
            asm volatile("s_waitcnt vmcnt(4)\n\ts_barrier" ::: "memory");
        }
    }

    // ---- epilogue: normalize and store FLAT [b*2048+s][h*128+d] ----
    const int bb = bh >> 4, hh = bh & 15;
    u16* Oh = Ob + (size_t)bb * 2048 * 2048 + (size_t)hh * 128;
    float linv = 1.f / lrun;
#pragma unroll
    for (int r = 0; r < 16; ++r) {
        int qr = (r & 3) + 8 * (r >> 2) + 4 * hi;
        float lr = __shfl(linv, qr);
        int qq = qbase + qr;
#pragma unroll
        for (int dc = 0; dc < 4; ++dc)
            Oh[(size_t)qq * 2048 + dc * 32 + ql] = f2bf(acc[dc][r] * lr);
    }
}

// ================= proj GEMM: 128x128 tile, 4-wave, 2 blocks/CU =============
// (round-9 state, kept byte-identical)
__global__ __launch_bounds__(256, 2) void gemm_proj(
        const u16* __restrict__ Ob, const u16* __restrict__ BT,
        const float* __restrict__ bias, float* __restrict__ out) {
    __shared__ __align__(16) u16 lA[2][128 * 64];   // 16KB x2
    __shared__ __align__(16) u16 lB[2][128 * 64];   // 16KB x2
    const int tid = threadIdx.x;
    const int lane = tid & 63, wave = tid >> 6;
    const int quad = lane >> 4, l16 = lane & 15;
    const int wm = wave >> 1, wn = wave & 1;
    const int bid = blockIdx.x;
    const int swz = (bid & 7) * 64 + (bid >> 3);     // XCD-chunked remap
    const int m0 = (swz >> 4) * 128, n0 = (swz & 15) * 128;
    const int sw = l16 & 7;
    const int c4 = tid & 7;
    f32x4 acc[4][4] = {};

    auto stageA = [&](int t1, int nb) {     // 128x64 from Ob, 4 loads/thread
#pragma unroll
        for (int j = 0; j < 4; ++j) {
            int row = (j * 256 + tid) >> 3;
            gl_lds16(Ob + (size_t)(m0 + row) * 2048 + t1 * 64 + ((c4 ^ (row & 7)) * 8),
                     &lA[nb][row * 64 + c4 * 8]);
        }
    };
    auto stageB = [&](int h, int t1, int nb) {  // 64 rows (bit5==h), 2 loads
#pragma unroll
        for (int j = 0; j < 2; ++j) {
            int rih = (j * 256 + tid) >> 3;
            int row = (rih & 31) + h * 32 + (rih >> 5) * 64;
            gl_lds16(BT + (size_t)(n0 + row) * 2048 + t1 * 64 + ((c4 ^ (row & 7)) * 8),
                     &lB[nb][row * 64 + c4 * 8]);
        }
    };

    // prologue: FIFO [B0:2][A:4][B1:2]
    stageB(0, 0, 0);
    asm volatile("" ::: "memory");
    stageA(0, 0);
    asm volatile("" ::: "memory");
    stageB(1, 0, 0);

    constexpr int NT = 32;
    for (int t = 0; t < NT; ++t) {
        const int buf = t & 1, nb = buf ^ 1;
        const bool pf = (t + 1 < NT);
        // W0: B0(t)+A(t) landed (B1(t):2 stay in flight)
        asm volatile("s_waitcnt vmcnt(2)\n\ts_barrier" ::: "memory");
        short8 af[4][2], bf0[2][2];
        const int abase = (wm * 64 + l16) * 64;
        const int bbase = (wn * 64 + l16) * 64;
#pragma unroll
        for (int m = 0; m < 4; ++m)
#pragma unroll
            for (int ks = 0; ks < 2; ++ks)
                af[m][ks] = *(const short8*)&lA[buf][abase + m * 1024 + (((ks * 4 + quad) ^ sw)) * 8];
#pragma unroll
        for (int n = 0; n < 2; ++n)
#pragma unroll
            for (int ks = 0; ks < 2; ++ks)
                bf0[n][ks] = *(const short8*)&lB[buf][bbase + n * 1024 + (((ks * 4 + quad) ^ sw)) * 8];
        if (pf) {
            stageB(0, t + 1, nb);
            asm volatile("" ::: "memory");
            stageA(t + 1, nb);
        }
        __builtin_amdgcn_s_setprio(1);
#pragma unroll
        for (int m = 0; m < 4; ++m)
#pragma unroll
            for (int n = 0; n < 2; ++n)
#pragma unroll
                for (int ks = 0; ks < 2; ++ks)
                    acc[m][n] = __builtin_amdgcn_mfma_f32_16x16x32_bf16(
                        af[m][ks], bf0[n][ks], acc[m][n], 0, 0, 0);
        __builtin_amdgcn_s_setprio(0);
        // W1: B1(t) landed (t+1's B0:2 + A:4 = 6 stay in flight)
        if (pf) asm volatile("s_waitcnt vmcnt(6)\n\ts_barrier" ::: "memory");
        else    asm volatile("s_waitcnt vmcnt(0)\n\ts_barrier" ::: "memory");
        short8 bf1[2][2];
#pragma unroll
        for (int n = 0; n < 2; ++n)
#pragma unroll
            for (int ks = 0; ks < 2; ++ks)
                bf1[n][ks] = *(const short8*)&lB[buf][bbase + 2048 + n * 1024 + (((ks * 4 + quad) ^ sw)) * 8];
        if (pf) stageB(1, t + 1, nb);
        __builtin_amdgcn_s_setprio(1);
#pragma unroll
        for (int m = 0; m < 4; ++m)
#pragma unroll
            for (int n = 0; n < 2; ++n)
#pragma unroll
                for (int ks = 0; ks < 2; ++ks)
                    acc[m][n + 2] = __builtin_amdgcn_mfma_f32_16x16x32_bf16(
                        af[m][ks], bf1[n][ks], acc[m][n + 2], 0, 0, 0);
        __builtin_amdgcn_s_setprio(0);
    }

    // ---- epilogue: fp32 + bias ----
#pragma unroll
    for (int m = 0; m < 4; ++m) {
        int r0r = m0 + wm * 64 + m * 16 + quad * 4;
#pragma unroll
        for (int n = 0; n < 4; ++n) {
            int cc = n0 + wn * 64 + n * 16 + l16;
            float bv = bias[cc];
#pragma unroll
            for (int rg = 0; rg < 4; ++rg)
                out[(size_t)(r0r + rg) * 2048 + cc] = acc[m][n][rg] + bv;
        }
    }
}

extern "C" void kernel_launch(void* const* d_in, const int* in_sizes, int n_in,
                              void* d_out, int out_size, void* d_ws, size_t ws_size,
                              hipStream_t stream) {
    const float *x = nullptr, *Wqkv = nullptr, *Wproj = nullptr, *bproj = nullptr;
    for (int i = 0; i < n_in; ++i) {
        int sz = in_sizes[i];
        if      (sz == 2 * 2048 * 2048) x     = (const float*)d_in[i];
        else if (sz == 2048 * 6144)     Wqkv  = (const float*)d_in[i];
        else if (sz == 2048 * 2048)     Wproj = (const float*)d_in[i];
        else if (sz == 2048)            bproj = (const float*)d_in[i];
    }
    float* out = (float*)d_out;

    // ws overlay (all bf16). Ob (flat attn output, 4096x2048) reuses xb's
    // region: x is consumed by gemm_qkv before attn_kern writes Ob.
    u16* xb     = (u16*)d_ws;
    u16* WqkvT  = xb    + (size_t)4096 * 2048;
    u16* Qb     = WqkvT + (size_t)6144 * 2048;
    u16* Kb     = Qb    + (size_t)32 * 2048 * 128;
    u16* VTb    = Kb    + (size_t)32 * 2048 * 128;
    u16* WprojT = VTb   + (size_t)32 * 2048 * 128;
    u16* Obuf   = xb;   // overlay: xb dead after gemm_qkv

    convx<<<dim3(4096), dim3(256), 0, stream>>>(x, xb);
    convT2<<<dim3(128, 32), dim3(256), 0, stream>>>(Wqkv, WqkvT, Wproj, WprojT);
    gemm_qkv<<<dim3(24, 32), dim3(512), 0, stream>>>(xb, WqkvT, Qb, Kb, VTb);
    attn_kern<<<dim3(32, 16), dim3(256), 0, stream>>>(Qb, Kb, VTb, Obuf);
    gemm_proj<<<dim3(512), dim3(256), 0, stream>>>(Obuf, WprojT, bproj, out);
}